// Round 1
// baseline (993.678 us; speedup 1.0000x reference)
//
#include <hip/hip_runtime.h>
#include <math.h>

#define B_    2
#define SEQ_  2048
#define D_    256
#define H_    8
#define DK_   32
#define L_    2
#define DFF_  1024

// ---------------------------------------------------------------------------
// Kernel 1: conv1d(K=3, SAME) + bias + bn-ish affine + relu + positional enc.
// h[b,s,d] = relu((sum_k x[b,s+k-1]*w[d,k] + cb[d]) * rsqrt(1+eps) * bg[d] + bb[d]) + pe[s,d]
// ---------------------------------------------------------------------------
__global__ __launch_bounds__(256) void conv_pe_kernel(
    const float* __restrict__ x, const float* __restrict__ w,
    const float* __restrict__ cb, const float* __restrict__ bg,
    const float* __restrict__ bb, const float* __restrict__ pe,
    float* __restrict__ h)
{
    int idx = blockIdx.x * 256 + threadIdx.x;      // b*SEQ*D + s*D + d
    int d = idx & 255;
    int s = (idx >> 8) & 2047;
    int b = idx >> 19;

    const float* xp = x + b * SEQ_;
    float xm1 = (s > 0)        ? xp[s - 1] : 0.f;
    float x0  = xp[s];
    float xp1 = (s < SEQ_ - 1) ? xp[s + 1] : 0.f;

    float acc = xm1 * w[d * 3 + 0] + x0 * w[d * 3 + 1] + xp1 * w[d * 3 + 2];
    acc += cb[d];
    acc = acc * rsqrtf(1.f + 1e-5f) * bg[d] + bb[d];
    acc = fmaxf(acc, 0.f);
    h[idx] = acc + pe[s * D_ + d];
}

// ---------------------------------------------------------------------------
// Kernel 2: SGEMM  C[m,n] = sum_k A[m,k]*B[n,k] + bias[n], optional relu.
// A: MxK row-major, B: NxK row-major (i.e. computes A @ B^T).
// BM=BN=64, BK=16, 256 threads, 4x4 microtile per thread.
// M,N div by 64; K div by 16.
// ---------------------------------------------------------------------------
#define BM 64
#define BN 64
#define BK 16
__global__ __launch_bounds__(256) void sgemm_bt(
    const float* __restrict__ A, const float* __restrict__ Bm,
    const float* __restrict__ bias, float* __restrict__ C,
    int M, int N, int K, int relu)
{
    __shared__ float As[BK][BM + 4];
    __shared__ float Bs[BK][BN + 4];

    int tid = threadIdx.x;
    int bm = blockIdx.y * BM;
    int bn = blockIdx.x * BN;
    int tx = tid & 15;         // 0..15 -> cols
    int ty = tid >> 4;         // 0..15 -> rows

    int lr = tid >> 2;         // 0..63 load row
    int lk = (tid & 3) * 4;    // 0,4,8,12 load k-offset

    float acc[4][4];
#pragma unroll
    for (int i = 0; i < 4; ++i)
#pragma unroll
        for (int j = 0; j < 4; ++j) acc[i][j] = 0.f;

    for (int k0 = 0; k0 < K; k0 += BK) {
        float4 av = *(const float4*)(A + (size_t)(bm + lr) * K + k0 + lk);
        float4 bv = *(const float4*)(Bm + (size_t)(bn + lr) * K + k0 + lk);
        As[lk + 0][lr] = av.x; As[lk + 1][lr] = av.y;
        As[lk + 2][lr] = av.z; As[lk + 3][lr] = av.w;
        Bs[lk + 0][lr] = bv.x; Bs[lk + 1][lr] = bv.y;
        Bs[lk + 2][lr] = bv.z; Bs[lk + 3][lr] = bv.w;
        __syncthreads();

#pragma unroll
        for (int kk = 0; kk < BK; ++kk) {
            float4 a4 = *(const float4*)&As[kk][ty * 4];
            float4 b4 = *(const float4*)&Bs[kk][tx * 4];
            float ar[4] = {a4.x, a4.y, a4.z, a4.w};
            float br[4] = {b4.x, b4.y, b4.z, b4.w};
#pragma unroll
            for (int i = 0; i < 4; ++i)
#pragma unroll
                for (int j = 0; j < 4; ++j) acc[i][j] += ar[i] * br[j];
        }
        __syncthreads();
    }

    float4 bi = *(const float4*)(bias + bn + tx * 4);
    float br[4] = {bi.x, bi.y, bi.z, bi.w};
#pragma unroll
    for (int i = 0; i < 4; ++i) {
        float4 o;
        float v0 = acc[i][0] + br[0], v1 = acc[i][1] + br[1];
        float v2 = acc[i][2] + br[2], v3 = acc[i][3] + br[3];
        if (relu) { v0 = fmaxf(v0, 0.f); v1 = fmaxf(v1, 0.f); v2 = fmaxf(v2, 0.f); v3 = fmaxf(v3, 0.f); }
        o.x = v0; o.y = v1; o.z = v2; o.w = v3;
        *(float4*)(C + (size_t)(bm + ty * 4 + i) * N + bn + tx * 4) = o;
    }
}

// ---------------------------------------------------------------------------
// Kernel 3: flash-style attention with decay + softmax*sigmoid weighting.
// grid: (SEQ/64, H, B), block 256 (4 waves).
// Each lane owns one query row; each wave handles a 512-key range (key-split 4);
// LDS merge of the 4 partials at the end.
// q,k,v,ctx are plain (B*SEQ, D) row-major; head hh uses cols [hh*32, hh*32+32).
// ---------------------------------------------------------------------------
__global__ __launch_bounds__(256) void attn_kernel(
    const float* __restrict__ q, const float* __restrict__ k,
    const float* __restrict__ v, float* __restrict__ ctx,
    const float* __restrict__ scale_p /*&scale[l]*/,
    const float* __restrict__ td_l /*&td[l*H]*/)
{
    int b = blockIdx.z, hh = blockIdx.y;
    int tid = threadIdx.x;
    int wave = tid >> 6;            // 0..3  key-split id
    int lane = tid & 63;
    int qrow = blockIdx.x * 64 + lane;

    float sc  = 0.17677669529663687f * scale_p[0];   // 1/sqrt(32) * scale[l]
    float tdv = td_l[hh];

    __shared__ float smem[8192];                    // kt(4096) | vt(4096); reused for merge
    float (*kt)[32][32] = (float (*)[32][32])smem;
    float (*vt)[32][32] = (float (*)[32][32])(smem + 4096);
    __shared__ float ms[4][64];
    __shared__ float ls[4][64];

    const float* qptr = q + ((size_t)(b * SEQ_ + qrow)) * D_ + hh * DK_;
    float qreg[32];
#pragma unroll
    for (int j = 0; j < 8; ++j) {
        float4 t4 = ((const float4*)qptr)[j];
        qreg[j * 4 + 0] = t4.x; qreg[j * 4 + 1] = t4.y;
        qreg[j * 4 + 2] = t4.z; qreg[j * 4 + 3] = t4.w;
    }
    float O[32];
#pragma unroll
    for (int d = 0; d < 32; ++d) O[d] = 0.f;
    float mrun = -1e30f, lrun = 0.f;

    int k0base = wave * 512;
    for (int t = 0; t < 16; ++t) {
        int k0 = k0base + t * 32;
        __syncthreads();
        // stage this wave's 32-key K/V tile: 32 rows x 32 floats each
#pragma unroll
        for (int u = 0; u < 4; ++u) {
            int idx = lane * 4 + u;            // 0..255 float4 slots
            int r = idx >> 3, c4 = idx & 7;
            size_t goff = ((size_t)(b * SEQ_ + k0 + r)) * D_ + hh * DK_ + c4 * 4;
            *(float4*)&kt[wave][r][c4 * 4] = *(const float4*)(k + goff);
            *(float4*)&vt[wave][r][c4 * 4] = *(const float4*)(v + goff);
        }
        __syncthreads();

#pragma unroll
        for (int c = 0; c < 2; ++c) {          // two 16-key chunks
            float sb[16];
            float tmax = -1e30f;
#pragma unroll
            for (int kk = 0; kk < 16; ++kk) {
                int kl = c * 16 + kk;
                float acc = 0.f;
#pragma unroll
                for (int d4 = 0; d4 < 8; ++d4) {
                    float4 kv = *(const float4*)&kt[wave][kl][d4 * 4];
                    acc += qreg[d4 * 4 + 0] * kv.x + qreg[d4 * 4 + 1] * kv.y
                         + qreg[d4 * 4 + 2] * kv.z + qreg[d4 * 4 + 3] * kv.w;
                }
                int kg = k0 + kl;
                float dec = __expf(-tdv * (float)kg);
                float sv = acc * sc * dec;
                sb[kk] = sv;
                tmax = fmaxf(tmax, sv);
            }
            float mnew = fmaxf(mrun, tmax);
            float alpha = __expf(mrun - mnew);
            lrun *= alpha;
#pragma unroll
            for (int d = 0; d < 32; ++d) O[d] *= alpha;
#pragma unroll
            for (int kk = 0; kk < 16; ++kk) {
                int kl = c * 16 + kk;
                float sv = sb[kk];
                float e = __expf(sv - mnew);
                float sg = 1.f / (1.f + __expf(-sv));
                float p = e * sg;
                lrun += e;
#pragma unroll
                for (int d4 = 0; d4 < 8; ++d4) {
                    float4 vv = *(const float4*)&vt[wave][kl][d4 * 4];
                    O[d4 * 4 + 0] += p * vv.x; O[d4 * 4 + 1] += p * vv.y;
                    O[d4 * 4 + 2] += p * vv.z; O[d4 * 4 + 3] += p * vv.w;
                }
            }
            mrun = mnew;
        }
    }

    // merge the 4 key-split partials via LDS (reuse smem: 4*64*32 = 8192 floats)
    __syncthreads();
    float* Os = smem;
#pragma unroll
    for (int d4 = 0; d4 < 8; ++d4) {
        float4 o4 = make_float4(O[d4 * 4 + 0], O[d4 * 4 + 1], O[d4 * 4 + 2], O[d4 * 4 + 3]);
        *(float4*)&Os[((size_t)(wave * 64 + lane)) * 32 + d4 * 4] = o4;
    }
    ms[wave][lane] = mrun;
    ls[wave][lane] = lrun;
    __syncthreads();

    {
        int r = lane, dg = wave;               // thread -> (row, 8-dim group)
        float m0 = fmaxf(fmaxf(ms[0][r], ms[1][r]), fmaxf(ms[2][r], ms[3][r]));
        float w0 = __expf(ms[0][r] - m0), w1 = __expf(ms[1][r] - m0);
        float w2 = __expf(ms[2][r] - m0), w3 = __expf(ms[3][r] - m0);
        float Lt = ls[0][r] * w0 + ls[1][r] * w1 + ls[2][r] * w2 + ls[3][r] * w3;
        float invL = 1.f / Lt;
        float* outp = ctx + ((size_t)(b * SEQ_ + blockIdx.x * 64 + r)) * D_ + hh * DK_ + dg * 8;
#pragma unroll
        for (int dd = 0; dd < 8; ++dd) {
            float val = (Os[(0 * 64 + r) * 32 + dg * 8 + dd] * w0
                       + Os[(1 * 64 + r) * 32 + dg * 8 + dd] * w1
                       + Os[(2 * 64 + r) * 32 + dg * 8 + dd] * w2
                       + Os[(3 * 64 + r) * 32 + dg * 8 + dd] * w3) * invL;
            outp[dd] = val;
        }
    }
}

// ---------------------------------------------------------------------------
// Kernel 4: out = LayerNorm(resid + add) * g + b, one wave per 256-elem row.
// ---------------------------------------------------------------------------
__global__ __launch_bounds__(256) void add_ln_kernel(
    const float* __restrict__ resid, const float* __restrict__ add,
    const float* __restrict__ g, const float* __restrict__ bta,
    float* __restrict__ out)
{
    int row = blockIdx.x * 4 + (threadIdx.x >> 6);
    int lane = threadIdx.x & 63;
    const float* rp = resid + (size_t)row * D_;
    const float* ap = add + (size_t)row * D_;
    float4 r4 = *(const float4*)(rp + lane * 4);
    float4 a4 = *(const float4*)(ap + lane * 4);
    float z0 = r4.x + a4.x, z1 = r4.y + a4.y, z2 = r4.z + a4.z, z3 = r4.w + a4.w;
    float s = z0 + z1 + z2 + z3;
    float ss = z0 * z0 + z1 * z1 + z2 * z2 + z3 * z3;
#pragma unroll
    for (int off = 1; off < 64; off <<= 1) {
        s += __shfl_xor(s, off);
        ss += __shfl_xor(ss, off);
    }
    float mean = s * (1.f / 256.f);
    float var = ss * (1.f / 256.f) - mean * mean;
    float inv = rsqrtf(var + 1e-5f);
    int d = lane * 4;
    float4 g4 = *(const float4*)(g + d);
    float4 b4 = *(const float4*)(bta + d);
    float4 o;
    o.x = (z0 - mean) * inv * g4.x + b4.x;
    o.y = (z1 - mean) * inv * g4.y + b4.y;
    o.z = (z2 - mean) * inv * g4.z + b4.z;
    o.w = (z3 - mean) * inv * g4.w + b4.w;
    *(float4*)(out + (size_t)row * D_ + d) = o;
}

// ---------------------------------------------------------------------------
// Kernel 5: out[b] = dot(h[b, SEQ-1, :], outW) * (1-0.5) + outb[0]
// ---------------------------------------------------------------------------
__global__ __launch_bounds__(128) void final_kernel(
    const float* __restrict__ h, const float* __restrict__ outW,
    const float* __restrict__ outb, float* __restrict__ out)
{
    int b = threadIdx.x >> 6, lane = threadIdx.x & 63;
    const float* hp = h + ((size_t)(b * SEQ_ + SEQ_ - 1)) * D_;
    float4 h4 = *(const float4*)(hp + lane * 4);
    float4 w4 = *(const float4*)(outW + lane * 4);
    float s = h4.x * w4.x + h4.y * w4.y + h4.z * w4.z + h4.w * w4.w;
#pragma unroll
    for (int off = 1; off < 64; off <<= 1) s += __shfl_xor(s, off);
    if (lane == 0) out[b] = s * 0.5f + outb[0];
}

// ---------------------------------------------------------------------------
extern "C" void kernel_launch(void* const* d_in, const int* in_sizes, int n_in,
                              void* d_out, int out_size, void* d_ws, size_t ws_size,
                              hipStream_t stream)
{
    (void)in_sizes; (void)n_in; (void)out_size; (void)ws_size;
    const float* x      = (const float*)d_in[0];
    const float* conv_w = (const float*)d_in[1];
    const float* conv_b = (const float*)d_in[2];
    const float* bn_g   = (const float*)d_in[3];
    const float* bn_b   = (const float*)d_in[4];
    const float* pe     = (const float*)d_in[5];
    const float* qW     = (const float*)d_in[6];
    const float* qb     = (const float*)d_in[7];
    const float* kW     = (const float*)d_in[8];
    const float* kb     = (const float*)d_in[9];
    const float* vW     = (const float*)d_in[10];
    const float* vb     = (const float*)d_in[11];
    const float* oW     = (const float*)d_in[12];
    const float* ob     = (const float*)d_in[13];
    const float* scale  = (const float*)d_in[14];
    const float* td     = (const float*)d_in[15];
    const float* ln1g   = (const float*)d_in[16];
    const float* ln1b   = (const float*)d_in[17];
    const float* f1W    = (const float*)d_in[18];
    const float* f1b    = (const float*)d_in[19];
    const float* f2W    = (const float*)d_in[20];
    const float* f2b    = (const float*)d_in[21];
    const float* ln2g   = (const float*)d_in[22];
    const float* ln2b   = (const float*)d_in[23];
    const float* outW   = (const float*)d_in[24];
    const float* outb   = (const float*)d_in[25];
    float* out = (float*)d_out;

    float* ws = (float*)d_ws;
    const size_t MT = (size_t)B_ * SEQ_ * D_;      // 1M floats
    float* h   = ws;
    float* qs  = ws + MT;
    float* ks  = ws + 2 * MT;
    float* vs  = ws + 3 * MT;
    float* ctx = ws + 4 * MT;
    float* tmp = ws + 5 * MT;
    float* ff1 = ws + 6 * MT;                      // 4M floats

    const int Mrows = B_ * SEQ_;                   // 4096

    conv_pe_kernel<<<(B_ * SEQ_ * D_) / 256, 256, 0, stream>>>(
        x, conv_w, conv_b, bn_g, bn_b, pe, h);

    for (int l = 0; l < L_; ++l) {
        dim3 gD(D_ / BN, Mrows / BM);              // 4 x 64
        sgemm_bt<<<gD, 256, 0, stream>>>(h, qW + l * D_ * D_, qb + l * D_, qs,
                                         Mrows, D_, D_, 0);
        sgemm_bt<<<gD, 256, 0, stream>>>(h, kW + l * D_ * D_, kb + l * D_, ks,
                                         Mrows, D_, D_, 0);
        sgemm_bt<<<gD, 256, 0, stream>>>(h, vW + l * D_ * D_, vb + l * D_, vs,
                                         Mrows, D_, D_, 0);

        attn_kernel<<<dim3(SEQ_ / 64, H_, B_), 256, 0, stream>>>(
            qs, ks, vs, ctx, scale + l, td + l * H_);

        sgemm_bt<<<gD, 256, 0, stream>>>(ctx, oW + l * D_ * D_, ob + l * D_, tmp,
                                         Mrows, D_, D_, 0);
        add_ln_kernel<<<Mrows / 4, 256, 0, stream>>>(h, tmp, ln1g + l * D_, ln1b + l * D_, h);

        dim3 gF1(DFF_ / BN, Mrows / BM);           // 16 x 64
        sgemm_bt<<<gF1, 256, 0, stream>>>(h, f1W + l * DFF_ * D_, f1b + l * DFF_, ff1,
                                          Mrows, DFF_, D_, 1);
        sgemm_bt<<<gD, 256, 0, stream>>>(ff1, f2W + l * D_ * DFF_, f2b + l * D_, tmp,
                                         Mrows, D_, DFF_, 0);
        add_ln_kernel<<<Mrows / 4, 256, 0, stream>>>(h, tmp, ln2g + l * D_, ln2b + l * D_, h);
    }

    final_kernel<<<1, 128, 0, stream>>>(h, outW, outb, out);
}

// Round 2
// 590.144 us; speedup vs baseline: 1.6838x; 1.6838x over previous
//
#include <hip/hip_runtime.h>
#include <math.h>

#define B_    2
#define SEQ_  2048
#define D_    256
#define H_    8
#define DK_   32
#define L_    2
#define DFF_  1024

// decay cutoff: exp(-44) ~ 8e-20, below fp32 noise for any plausible score scale
#define TD_CUT 44.0f

__device__ __forceinline__ int compute_kcut(float tdv) {
    int kcut = SEQ_;
    if (tdv > 1e-9f) {
        float kc = TD_CUT / tdv;
        kcut = (kc >= (float)SEQ_) ? SEQ_ : ((int)kc + 1);
    }
    int kcr = (kcut + 31) & ~31;          // round up to tile size
    if (kcr > SEQ_) kcr = SEQ_;
    return kcr;
}

// ---------------------------------------------------------------------------
// Kernel 1: conv1d(K=3, SAME) + bias + bn-ish affine + relu + positional enc.
// ---------------------------------------------------------------------------
__global__ __launch_bounds__(256) void conv_pe_kernel(
    const float* __restrict__ x, const float* __restrict__ w,
    const float* __restrict__ cb, const float* __restrict__ bg,
    const float* __restrict__ bb, const float* __restrict__ pe,
    float* __restrict__ h)
{
    int idx = blockIdx.x * 256 + threadIdx.x;      // b*SEQ*D + s*D + d
    int d = idx & 255;
    int s = (idx >> 8) & 2047;
    int b = idx >> 19;

    const float* xp = x + b * SEQ_;
    float xm1 = (s > 0)        ? xp[s - 1] : 0.f;
    float x0  = xp[s];
    float xp1 = (s < SEQ_ - 1) ? xp[s + 1] : 0.f;

    float acc = xm1 * w[d * 3 + 0] + x0 * w[d * 3 + 1] + xp1 * w[d * 3 + 2];
    acc += cb[d];
    acc = acc * rsqrtf(1.f + 1e-5f) * bg[d] + bb[d];
    acc = fmaxf(acc, 0.f);
    h[idx] = acc + pe[s * D_ + d];
}

// ---------------------------------------------------------------------------
// Kernel 2: SGEMM  C[m,n] = sum_k A[m,k]*B[n,k] + bias[n], optional relu.
// ---------------------------------------------------------------------------
#define BM 64
#define BN 64
#define BK 16
__global__ __launch_bounds__(256) void sgemm_bt(
    const float* __restrict__ A, const float* __restrict__ Bm,
    const float* __restrict__ bias, float* __restrict__ C,
    int M, int N, int K, int relu)
{
    __shared__ float As[BK][BM + 4];
    __shared__ float Bs[BK][BN + 4];

    int tid = threadIdx.x;
    int bm = blockIdx.y * BM;
    int bn = blockIdx.x * BN;
    int tx = tid & 15;
    int ty = tid >> 4;

    int lr = tid >> 2;
    int lk = (tid & 3) * 4;

    float acc[4][4];
#pragma unroll
    for (int i = 0; i < 4; ++i)
#pragma unroll
        for (int j = 0; j < 4; ++j) acc[i][j] = 0.f;

    for (int k0 = 0; k0 < K; k0 += BK) {
        float4 av = *(const float4*)(A + (size_t)(bm + lr) * K + k0 + lk);
        float4 bv = *(const float4*)(Bm + (size_t)(bn + lr) * K + k0 + lk);
        As[lk + 0][lr] = av.x; As[lk + 1][lr] = av.y;
        As[lk + 2][lr] = av.z; As[lk + 3][lr] = av.w;
        Bs[lk + 0][lr] = bv.x; Bs[lk + 1][lr] = bv.y;
        Bs[lk + 2][lr] = bv.z; Bs[lk + 3][lr] = bv.w;
        __syncthreads();

#pragma unroll
        for (int kk = 0; kk < BK; ++kk) {
            float4 a4 = *(const float4*)&As[kk][ty * 4];
            float4 b4 = *(const float4*)&Bs[kk][tx * 4];
            float ar[4] = {a4.x, a4.y, a4.z, a4.w};
            float br[4] = {b4.x, b4.y, b4.z, b4.w};
#pragma unroll
            for (int i = 0; i < 4; ++i)
#pragma unroll
                for (int j = 0; j < 4; ++j) acc[i][j] += ar[i] * br[j];
        }
        __syncthreads();
    }

    float4 bi = *(const float4*)(bias + bn + tx * 4);
    float br[4] = {bi.x, bi.y, bi.z, bi.w};
#pragma unroll
    for (int i = 0; i < 4; ++i) {
        float4 o;
        float v0 = acc[i][0] + br[0], v1 = acc[i][1] + br[1];
        float v2 = acc[i][2] + br[2], v3 = acc[i][3] + br[3];
        if (relu) { v0 = fmaxf(v0, 0.f); v1 = fmaxf(v1, 0.f); v2 = fmaxf(v2, 0.f); v3 = fmaxf(v3, 0.f); }
        o.x = v0; o.y = v1; o.z = v2; o.w = v3;
        *(float4*)(C + (size_t)(bm + ty * 4 + i) * N + bn + tx * 4) = o;
    }
}

// ---------------------------------------------------------------------------
// Kernel 3a: V-suffix sums. vtail[b][h][d] = sum_{k >= kcut(h)} v[b,k,h*32+d]
// grid (H, B), 256 threads: dim d = tid&31, row-chunk c = tid>>5 (8 chunks).
// ---------------------------------------------------------------------------
__global__ __launch_bounds__(256) void vtail_kernel(
    const float* __restrict__ v, const float* __restrict__ td_l,
    float* __restrict__ vtail)
{
    int hh = blockIdx.x, b = blockIdx.y;
    int d = threadIdx.x & 31, c = threadIdx.x >> 5;
    int kcr = compute_kcut(td_l[hh]);

    float s = 0.f;
    for (int k = kcr + c; k < SEQ_; k += 8)
        s += v[((size_t)(b * SEQ_ + k)) * D_ + hh * DK_ + d];

    __shared__ float sm[8][32];
    sm[c][d] = s;
    __syncthreads();
    if (threadIdx.x < 32) {
        float t = 0.f;
#pragma unroll
        for (int i = 0; i < 8; ++i) t += sm[i][threadIdx.x];
        vtail[((size_t)(b * H_ + hh)) * DK_ + threadIdx.x] = t;
    }
}

// ---------------------------------------------------------------------------
// Kernel 3b: decay-truncated flash attention + analytic tail.
// grid (SEQ/128, H, B), 128 threads, one query row per thread.
// Keys [0, kcut) processed exactly in 32-key LDS tiles; keys >= kcut have
// score*decay == 0 in fp32, contributing exp(-m) to the denom and
// 0.5*exp(-m)*vtail to the numerator.
// ---------------------------------------------------------------------------
__global__ __launch_bounds__(128) void attn_kernel(
    const float* __restrict__ q, const float* __restrict__ k,
    const float* __restrict__ v, const float* __restrict__ vtail,
    float* __restrict__ ctx,
    const float* __restrict__ scale_p, const float* __restrict__ td_l)
{
    int b = blockIdx.z, hh = blockIdx.y;
    int tid = threadIdx.x;
    int qrow = blockIdx.x * 128 + tid;

    float sc  = 0.17677669529663687f * scale_p[0];   // 1/sqrt(32) * scale[l]
    float tdv = td_l[hh];
    int kcr = compute_kcut(tdv);
    int ntiles = kcr >> 5;

    __shared__ float kt[32][36];
    __shared__ float vt[32][36];

    const float* qptr = q + ((size_t)(b * SEQ_ + qrow)) * D_ + hh * DK_;
    float qreg[32];
#pragma unroll
    for (int j = 0; j < 8; ++j) {
        float4 t4 = ((const float4*)qptr)[j];
        qreg[j * 4 + 0] = t4.x; qreg[j * 4 + 1] = t4.y;
        qreg[j * 4 + 2] = t4.z; qreg[j * 4 + 3] = t4.w;
    }
    float O[32];
#pragma unroll
    for (int d = 0; d < 32; ++d) O[d] = 0.f;
    float mrun = -1e30f, lrun = 0.f;

    for (int t = 0; t < ntiles; ++t) {
        int k0 = t * 32;
        __syncthreads();
        // stage 32-key K/V tile: 256 float4 slots each, 128 threads x 2 slots
#pragma unroll
        for (int u = 0; u < 2; ++u) {
            int s4 = tid + u * 128;
            int r = s4 >> 3, c4 = s4 & 7;
            size_t goff = ((size_t)(b * SEQ_ + k0 + r)) * D_ + hh * DK_ + c4 * 4;
            *(float4*)&kt[r][c4 * 4] = *(const float4*)(k + goff);
            *(float4*)&vt[r][c4 * 4] = *(const float4*)(v + goff);
        }
        __syncthreads();

        float sb[32];
        float tmax = -1e30f;
#pragma unroll
        for (int kk = 0; kk < 32; ++kk) {
            float acc = 0.f;
#pragma unroll
            for (int d4 = 0; d4 < 8; ++d4) {
                float4 kv = *(const float4*)&kt[kk][d4 * 4];
                acc += qreg[d4 * 4 + 0] * kv.x + qreg[d4 * 4 + 1] * kv.y
                     + qreg[d4 * 4 + 2] * kv.z + qreg[d4 * 4 + 3] * kv.w;
            }
            float dec = __expf(-tdv * (float)(k0 + kk));
            float sv = acc * sc * dec;
            sb[kk] = sv;
            tmax = fmaxf(tmax, sv);
        }
        float mnew = fmaxf(mrun, tmax);
        float alpha = __expf(mrun - mnew);
        lrun *= alpha;
#pragma unroll
        for (int d = 0; d < 32; ++d) O[d] *= alpha;
#pragma unroll
        for (int kk = 0; kk < 32; ++kk) {
            float sv = sb[kk];
            float e = __expf(sv - mnew);
            float sg = 1.f / (1.f + __expf(-sv));
            float p = e * sg;
            lrun += e;
#pragma unroll
            for (int d4 = 0; d4 < 8; ++d4) {
                float4 vv = *(const float4*)&vt[kk][d4 * 4];
                O[d4 * 4 + 0] += p * vv.x; O[d4 * 4 + 1] += p * vv.y;
                O[d4 * 4 + 2] += p * vv.z; O[d4 * 4 + 3] += p * vv.w;
            }
        }
        mrun = mnew;
    }

    // analytic tail: all keys >= kcr have score exactly 0 (decay underflow)
    if (kcr < SEQ_) {
        float mnew = fmaxf(mrun, 0.f);
        float alpha = __expf(mrun - mnew);
        lrun *= alpha;
        float ew = __expf(-mnew);            // exp(0 - mnew)
        lrun += (float)(SEQ_ - kcr) * ew;
        const float* vtp = vtail + ((size_t)(b * H_ + hh)) * DK_;
        float pw = 0.5f * ew;                // sigmoid(0) = 0.5
#pragma unroll
        for (int d = 0; d < 32; ++d) O[d] = O[d] * alpha + pw * vtp[d];
    }

    float invL = 1.f / lrun;
    float* outp = ctx + ((size_t)(b * SEQ_ + qrow)) * D_ + hh * DK_;
#pragma unroll
    for (int d4 = 0; d4 < 8; ++d4) {
        float4 o;
        o.x = O[d4 * 4 + 0] * invL; o.y = O[d4 * 4 + 1] * invL;
        o.z = O[d4 * 4 + 2] * invL; o.w = O[d4 * 4 + 3] * invL;
        ((float4*)outp)[d4] = o;
    }
}

// ---------------------------------------------------------------------------
// Kernel 4: out = LayerNorm(resid + add) * g + b, one wave per 256-elem row.
// ---------------------------------------------------------------------------
__global__ __launch_bounds__(256) void add_ln_kernel(
    const float* __restrict__ resid, const float* __restrict__ add,
    const float* __restrict__ g, const float* __restrict__ bta,
    float* __restrict__ out)
{
    int row = blockIdx.x * 4 + (threadIdx.x >> 6);
    int lane = threadIdx.x & 63;
    const float* rp = resid + (size_t)row * D_;
    const float* ap = add + (size_t)row * D_;
    float4 r4 = *(const float4*)(rp + lane * 4);
    float4 a4 = *(const float4*)(ap + lane * 4);
    float z0 = r4.x + a4.x, z1 = r4.y + a4.y, z2 = r4.z + a4.z, z3 = r4.w + a4.w;
    float s = z0 + z1 + z2 + z3;
    float ss = z0 * z0 + z1 * z1 + z2 * z2 + z3 * z3;
#pragma unroll
    for (int off = 1; off < 64; off <<= 1) {
        s += __shfl_xor(s, off);
        ss += __shfl_xor(ss, off);
    }
    float mean = s * (1.f / 256.f);
    float var = ss * (1.f / 256.f) - mean * mean;
    float inv = rsqrtf(var + 1e-5f);
    int d = lane * 4;
    float4 g4 = *(const float4*)(g + d);
    float4 b4 = *(const float4*)(bta + d);
    float4 o;
    o.x = (z0 - mean) * inv * g4.x + b4.x;
    o.y = (z1 - mean) * inv * g4.y + b4.y;
    o.z = (z2 - mean) * inv * g4.z + b4.z;
    o.w = (z3 - mean) * inv * g4.w + b4.w;
    *(float4*)(out + (size_t)row * D_ + d) = o;
}

// ---------------------------------------------------------------------------
// Kernel 5: out[b] = dot(h[b, SEQ-1, :], outW) * (1-0.5) + outb[0]
// ---------------------------------------------------------------------------
__global__ __launch_bounds__(128) void final_kernel(
    const float* __restrict__ h, const float* __restrict__ outW,
    const float* __restrict__ outb, float* __restrict__ out)
{
    int b = threadIdx.x >> 6, lane = threadIdx.x & 63;
    const float* hp = h + ((size_t)(b * SEQ_ + SEQ_ - 1)) * D_;
    float4 h4 = *(const float4*)(hp + lane * 4);
    float4 w4 = *(const float4*)(outW + lane * 4);
    float s = h4.x * w4.x + h4.y * w4.y + h4.z * w4.z + h4.w * w4.w;
#pragma unroll
    for (int off = 1; off < 64; off <<= 1) s += __shfl_xor(s, off);
    if (lane == 0) out[b] = s * 0.5f + outb[0];
}

// ---------------------------------------------------------------------------
extern "C" void kernel_launch(void* const* d_in, const int* in_sizes, int n_in,
                              void* d_out, int out_size, void* d_ws, size_t ws_size,
                              hipStream_t stream)
{
    (void)in_sizes; (void)n_in; (void)out_size; (void)ws_size;
    const float* x      = (const float*)d_in[0];
    const float* conv_w = (const float*)d_in[1];
    const float* conv_b = (const float*)d_in[2];
    const float* bn_g   = (const float*)d_in[3];
    const float* bn_b   = (const float*)d_in[4];
    const float* pe     = (const float*)d_in[5];
    const float* qW     = (const float*)d_in[6];
    const float* qb     = (const float*)d_in[7];
    const float* kW     = (const float*)d_in[8];
    const float* kb     = (const float*)d_in[9];
    const float* vW     = (const float*)d_in[10];
    const float* vb     = (const float*)d_in[11];
    const float* oW     = (const float*)d_in[12];
    const float* ob     = (const float*)d_in[13];
    const float* scale  = (const float*)d_in[14];
    const float* td     = (const float*)d_in[15];
    const float* ln1g   = (const float*)d_in[16];
    const float* ln1b   = (const float*)d_in[17];
    const float* f1W    = (const float*)d_in[18];
    const float* f1b    = (const float*)d_in[19];
    const float* f2W    = (const float*)d_in[20];
    const float* f2b    = (const float*)d_in[21];
    const float* ln2g   = (const float*)d_in[22];
    const float* ln2b   = (const float*)d_in[23];
    const float* outW   = (const float*)d_in[24];
    const float* outb   = (const float*)d_in[25];
    float* out = (float*)d_out;

    float* ws = (float*)d_ws;
    const size_t MT = (size_t)B_ * SEQ_ * D_;      // 1M floats
    float* h   = ws;
    float* qs  = ws + MT;
    float* ks  = ws + 2 * MT;
    float* vs  = ws + 3 * MT;
    float* ctx = ws + 4 * MT;
    float* tmp = ws + 5 * MT;
    float* ff1 = ws + 6 * MT;                      // 4M floats
    float* vtail = ws + 10 * MT;                   // B*H*32 floats

    const int Mrows = B_ * SEQ_;                   // 4096

    conv_pe_kernel<<<(B_ * SEQ_ * D_) / 256, 256, 0, stream>>>(
        x, conv_w, conv_b, bn_g, bn_b, pe, h);

    for (int l = 0; l < L_; ++l) {
        dim3 gD(D_ / BN, Mrows / BM);              // 4 x 64
        sgemm_bt<<<gD, 256, 0, stream>>>(h, qW + l * D_ * D_, qb + l * D_, qs,
                                         Mrows, D_, D_, 0);
        sgemm_bt<<<gD, 256, 0, stream>>>(h, kW + l * D_ * D_, kb + l * D_, ks,
                                         Mrows, D_, D_, 0);
        sgemm_bt<<<gD, 256, 0, stream>>>(h, vW + l * D_ * D_, vb + l * D_, vs,
                                         Mrows, D_, D_, 0);

        vtail_kernel<<<dim3(H_, B_), 256, 0, stream>>>(vs, td + l * H_, vtail);
        attn_kernel<<<dim3(SEQ_ / 128, H_, B_), 128, 0, stream>>>(
            qs, ks, vs, vtail, ctx, scale + l, td + l * H_);

        sgemm_bt<<<gD, 256, 0, stream>>>(ctx, oW + l * D_ * D_, ob + l * D_, tmp,
                                         Mrows, D_, D_, 0);
        add_ln_kernel<<<Mrows / 4, 256, 0, stream>>>(h, tmp, ln1g + l * D_, ln1b + l * D_, h);

        dim3 gF1(DFF_ / BN, Mrows / BM);           // 16 x 64
        sgemm_bt<<<gF1, 256, 0, stream>>>(h, f1W + l * DFF_ * D_, f1b + l * DFF_, ff1,
                                          Mrows, DFF_, D_, 1);
        sgemm_bt<<<gD, 256, 0, stream>>>(ff1, f2W + l * D_ * DFF_, f2b + l * D_, tmp,
                                         Mrows, D_, DFF_, 0);
        add_ln_kernel<<<Mrows / 4, 256, 0, stream>>>(h, tmp, ln2g + l * D_, ln2b + l * D_, h);
    }

    final_kernel<<<1, 128, 0, stream>>>(h, outW, outb, out);
}

// Round 3
// 358.180 us; speedup vs baseline: 2.7742x; 1.6476x over previous
//
#include <hip/hip_runtime.h>
#include <math.h>

#define B_    2
#define SEQ_  2048
#define D_    256
#define H_    8
#define DK_   32
#define L_    2
#define DFF_  1024

// decay cutoff: exp(-44) ~ 8e-20, below fp32 noise for any plausible score scale
#define TD_CUT 44.0f

typedef short  bf16x8 __attribute__((ext_vector_type(8)));
typedef float  f32x4  __attribute__((ext_vector_type(4)));

__device__ __forceinline__ int compute_kcut(float tdv) {
    int kcut = SEQ_;
    if (tdv > 1e-9f) {
        float kc = TD_CUT / tdv;
        kcut = (kc >= (float)SEQ_) ? SEQ_ : ((int)kc + 1);
    }
    int kcr = (kcut + 31) & ~31;          // round up to tile size
    if (kcr > SEQ_) kcr = SEQ_;
    return kcr;
}

__device__ __forceinline__ unsigned short f2bf(float f) {
    unsigned int u = __float_as_uint(f);
    unsigned int r = u + 0x7FFFu + ((u >> 16) & 1u);   // round-to-nearest-even
    return (unsigned short)(r >> 16);
}

// ---------------------------------------------------------------------------
// Kernel 1: conv1d(K=3, SAME) + bias + bn-ish affine + relu + positional enc.
// ---------------------------------------------------------------------------
__global__ __launch_bounds__(256) void conv_pe_kernel(
    const float* __restrict__ x, const float* __restrict__ w,
    const float* __restrict__ cb, const float* __restrict__ bg,
    const float* __restrict__ bb, const float* __restrict__ pe,
    float* __restrict__ h)
{
    int idx = blockIdx.x * 256 + threadIdx.x;      // b*SEQ*D + s*D + d
    int d = idx & 255;
    int s = (idx >> 8) & 2047;
    int b = idx >> 19;

    const float* xp = x + b * SEQ_;
    float xm1 = (s > 0)        ? xp[s - 1] : 0.f;
    float x0  = xp[s];
    float xp1 = (s < SEQ_ - 1) ? xp[s + 1] : 0.f;

    float acc = xm1 * w[d * 3 + 0] + x0 * w[d * 3 + 1] + xp1 * w[d * 3 + 2];
    acc += cb[d];
    acc = acc * rsqrtf(1.f + 1e-5f) * bg[d] + bb[d];
    acc = fmaxf(acc, 0.f);
    h[idx] = acc + pe[s * D_ + d];
}

// ---------------------------------------------------------------------------
// Kernel 2: bf16-MFMA GEMM  C[m,n] = sum_k A[m,k]*B[n,k] + bias[n], opt relu.
// A: MxK fp32 row-major, B: NxK fp32 row-major (A @ B^T). fp32 out.
// 64x64 block tile, BK=32, 256 threads = 4 waves in 2x2, wave tile 32x32.
// mfma_f32_16x16x32_bf16: A/B frag = [m=lane&15][k=(lane>>4)*8+j],
//                         C/D frag = col=lane&15, row=(lane>>4)*4+reg.
// LDS rows padded to 40 shorts (80 B) -> frag reads hit 8 accesses/bank (min).
// ---------------------------------------------------------------------------
__global__ __launch_bounds__(256) void gemm_bf16(
    const float* __restrict__ A, const float* __restrict__ Bm,
    const float* __restrict__ bias, float* __restrict__ C,
    int M, int N, int K, int relu)
{
    __shared__ unsigned short As[64 * 40];
    __shared__ unsigned short Bs[64 * 40];

    int tid  = threadIdx.x;
    int wave = tid >> 6, lane = tid & 63;
    int wm = (wave & 1) * 32, wn = (wave >> 1) * 32;
    int bm = blockIdx.y * 64, bn = blockIdx.x * 64;

    int lr = tid >> 2;            // 0..63 staging row
    int lc = (tid & 3) * 8;       // 0,8,16,24 staging col

    int fr = lane & 15;           // fragment row-within-16
    int fk = (lane >> 4) * 8;     // fragment k-offset

    f32x4 acc[2][2];
#pragma unroll
    for (int i = 0; i < 2; ++i)
#pragma unroll
        for (int j = 0; j < 2; ++j) acc[i][j] = (f32x4){0.f, 0.f, 0.f, 0.f};

    const float* ap = A  + (size_t)(bm + lr) * K + lc;
    const float* bp = Bm + (size_t)(bn + lr) * K + lc;

    for (int k0 = 0; k0 < K; k0 += 32) {
        float4 a0 = *(const float4*)(ap + k0);
        float4 a1 = *(const float4*)(ap + k0 + 4);
        float4 b0 = *(const float4*)(bp + k0);
        float4 b1 = *(const float4*)(bp + k0 + 4);

        __syncthreads();          // previous iteration's frag reads done
        bf16x8 apk, bpk;
        apk[0]=(short)f2bf(a0.x); apk[1]=(short)f2bf(a0.y);
        apk[2]=(short)f2bf(a0.z); apk[3]=(short)f2bf(a0.w);
        apk[4]=(short)f2bf(a1.x); apk[5]=(short)f2bf(a1.y);
        apk[6]=(short)f2bf(a1.z); apk[7]=(short)f2bf(a1.w);
        bpk[0]=(short)f2bf(b0.x); bpk[1]=(short)f2bf(b0.y);
        bpk[2]=(short)f2bf(b0.z); bpk[3]=(short)f2bf(b0.w);
        bpk[4]=(short)f2bf(b1.x); bpk[5]=(short)f2bf(b1.y);
        bpk[6]=(short)f2bf(b1.z); bpk[7]=(short)f2bf(b1.w);
        *(bf16x8*)&As[lr * 40 + lc] = apk;
        *(bf16x8*)&Bs[lr * 40 + lc] = bpk;
        __syncthreads();

        bf16x8 a0f = *(const bf16x8*)&As[(wm +      fr) * 40 + fk];
        bf16x8 a1f = *(const bf16x8*)&As[(wm + 16 + fr) * 40 + fk];
        bf16x8 b0f = *(const bf16x8*)&Bs[(wn +      fr) * 40 + fk];
        bf16x8 b1f = *(const bf16x8*)&Bs[(wn + 16 + fr) * 40 + fk];

        acc[0][0] = __builtin_amdgcn_mfma_f32_16x16x32_bf16(a0f, b0f, acc[0][0], 0, 0, 0);
        acc[0][1] = __builtin_amdgcn_mfma_f32_16x16x32_bf16(a0f, b1f, acc[0][1], 0, 0, 0);
        acc[1][0] = __builtin_amdgcn_mfma_f32_16x16x32_bf16(a1f, b0f, acc[1][0], 0, 0, 0);
        acc[1][1] = __builtin_amdgcn_mfma_f32_16x16x32_bf16(a1f, b1f, acc[1][1], 0, 0, 0);
    }

    int crow = (lane >> 4) * 4;
    int ccol = lane & 15;
#pragma unroll
    for (int j = 0; j < 2; ++j) {
        float bj = bias[bn + wn + j * 16 + ccol];
#pragma unroll
        for (int i = 0; i < 2; ++i) {
#pragma unroll
            for (int r = 0; r < 4; ++r) {
                float v = acc[i][j][r] + bj;
                if (relu) v = fmaxf(v, 0.f);
                C[(size_t)(bm + wm + i * 16 + crow + r) * N + bn + wn + j * 16 + ccol] = v;
            }
        }
    }
}

// ---------------------------------------------------------------------------
// Kernel 3a: V-suffix sums. vtail[b][h][d] = sum_{k >= kcut(h)} v[b,k,h*32+d]
// grid (H, B, 32): z-block sums rows [z*64, z*64+64) ∩ [kcut, SEQ),
// atomicAdd partial into vtail (caller zeroes vtail via hipMemsetAsync).
// ---------------------------------------------------------------------------
__global__ __launch_bounds__(256) void vtail_kernel(
    const float* __restrict__ v, const float* __restrict__ td_l,
    float* __restrict__ vtail)
{
    int hh = blockIdx.x, b = blockIdx.y, z = blockIdx.z;
    int kcr = compute_kcut(td_l[hh]);
    int rbeg = z * 64, rend = rbeg + 64;
    if (rend <= kcr) return;
    int lo = rbeg > kcr ? rbeg : kcr;

    int d = threadIdx.x & 31, c = threadIdx.x >> 5;    // 8 row-chunks
    float s = 0.f;
    for (int k = lo + c; k < rend; k += 8)
        s += v[((size_t)(b * SEQ_ + k)) * D_ + hh * DK_ + d];

    __shared__ float sm[8][32];
    sm[c][d] = s;
    __syncthreads();
    if (threadIdx.x < 32) {
        float t = 0.f;
#pragma unroll
        for (int i = 0; i < 8; ++i) t += sm[i][threadIdx.x];
        atomicAdd(&vtail[((size_t)(b * H_ + hh)) * DK_ + threadIdx.x], t);
    }
}

// ---------------------------------------------------------------------------
// Kernel 3b: decay-truncated flash attention + analytic tail.
// ---------------------------------------------------------------------------
__global__ __launch_bounds__(128) void attn_kernel(
    const float* __restrict__ q, const float* __restrict__ k,
    const float* __restrict__ v, const float* __restrict__ vtail,
    float* __restrict__ ctx,
    const float* __restrict__ scale_p, const float* __restrict__ td_l)
{
    int b = blockIdx.z, hh = blockIdx.y;
    int tid = threadIdx.x;
    int qrow = blockIdx.x * 128 + tid;

    float sc  = 0.17677669529663687f * scale_p[0];   // 1/sqrt(32) * scale[l]
    float tdv = td_l[hh];
    int kcr = compute_kcut(tdv);
    int ntiles = kcr >> 5;

    __shared__ float kt[32][36];
    __shared__ float vt[32][36];

    const float* qptr = q + ((size_t)(b * SEQ_ + qrow)) * D_ + hh * DK_;
    float qreg[32];
#pragma unroll
    for (int j = 0; j < 8; ++j) {
        float4 t4 = ((const float4*)qptr)[j];
        qreg[j * 4 + 0] = t4.x; qreg[j * 4 + 1] = t4.y;
        qreg[j * 4 + 2] = t4.z; qreg[j * 4 + 3] = t4.w;
    }
    float O[32];
#pragma unroll
    for (int d = 0; d < 32; ++d) O[d] = 0.f;
    float mrun = -1e30f, lrun = 0.f;

    for (int t = 0; t < ntiles; ++t) {
        int k0 = t * 32;
        __syncthreads();
#pragma unroll
        for (int u = 0; u < 2; ++u) {
            int s4 = tid + u * 128;
            int r = s4 >> 3, c4 = s4 & 7;
            size_t goff = ((size_t)(b * SEQ_ + k0 + r)) * D_ + hh * DK_ + c4 * 4;
            *(float4*)&kt[r][c4 * 4] = *(const float4*)(k + goff);
            *(float4*)&vt[r][c4 * 4] = *(const float4*)(v + goff);
        }
        __syncthreads();

        float sb[32];
        float tmax = -1e30f;
#pragma unroll
        for (int kk = 0; kk < 32; ++kk) {
            float acc = 0.f;
#pragma unroll
            for (int d4 = 0; d4 < 8; ++d4) {
                float4 kv = *(const float4*)&kt[kk][d4 * 4];
                acc += qreg[d4 * 4 + 0] * kv.x + qreg[d4 * 4 + 1] * kv.y
                     + qreg[d4 * 4 + 2] * kv.z + qreg[d4 * 4 + 3] * kv.w;
            }
            float dec = __expf(-tdv * (float)(k0 + kk));
            float sv = acc * sc * dec;
            sb[kk] = sv;
            tmax = fmaxf(tmax, sv);
        }
        float mnew = fmaxf(mrun, tmax);
        float alpha = __expf(mrun - mnew);
        lrun *= alpha;
#pragma unroll
        for (int d = 0; d < 32; ++d) O[d] *= alpha;
#pragma unroll
        for (int kk = 0; kk < 32; ++kk) {
            float sv = sb[kk];
            float e = __expf(sv - mnew);
            float sg = 1.f / (1.f + __expf(-sv));
            float p = e * sg;
            lrun += e;
#pragma unroll
            for (int d4 = 0; d4 < 8; ++d4) {
                float4 vv = *(const float4*)&vt[kk][d4 * 4];
                O[d4 * 4 + 0] += p * vv.x; O[d4 * 4 + 1] += p * vv.y;
                O[d4 * 4 + 2] += p * vv.z; O[d4 * 4 + 3] += p * vv.w;
            }
        }
        mrun = mnew;
    }

    // analytic tail: all keys >= kcr have score exactly 0 (decay underflow)
    if (kcr < SEQ_) {
        float mnew = fmaxf(mrun, 0.f);
        float alpha = __expf(mrun - mnew);
        lrun *= alpha;
        float ew = __expf(-mnew);
        lrun += (float)(SEQ_ - kcr) * ew;
        const float* vtp = vtail + ((size_t)(b * H_ + hh)) * DK_;
        float pw = 0.5f * ew;                // sigmoid(0) = 0.5
#pragma unroll
        for (int d = 0; d < 32; ++d) O[d] = O[d] * alpha + pw * vtp[d];
    }

    float invL = 1.f / lrun;
    float* outp = ctx + ((size_t)(b * SEQ_ + qrow)) * D_ + hh * DK_;
#pragma unroll
    for (int d4 = 0; d4 < 8; ++d4) {
        float4 o;
        o.x = O[d4 * 4 + 0] * invL; o.y = O[d4 * 4 + 1] * invL;
        o.z = O[d4 * 4 + 2] * invL; o.w = O[d4 * 4 + 3] * invL;
        ((float4*)outp)[d4] = o;
    }
}

// ---------------------------------------------------------------------------
// Kernel 4: out = LayerNorm(resid + add) * g + b, one wave per 256-elem row.
// ---------------------------------------------------------------------------
__global__ __launch_bounds__(256) void add_ln_kernel(
    const float* __restrict__ resid, const float* __restrict__ add,
    const float* __restrict__ g, const float* __restrict__ bta,
    float* __restrict__ out)
{
    int row = blockIdx.x * 4 + (threadIdx.x >> 6);
    int lane = threadIdx.x & 63;
    const float* rp = resid + (size_t)row * D_;
    const float* ap = add + (size_t)row * D_;
    float4 r4 = *(const float4*)(rp + lane * 4);
    float4 a4 = *(const float4*)(ap + lane * 4);
    float z0 = r4.x + a4.x, z1 = r4.y + a4.y, z2 = r4.z + a4.z, z3 = r4.w + a4.w;
    float s = z0 + z1 + z2 + z3;
    float ss = z0 * z0 + z1 * z1 + z2 * z2 + z3 * z3;
#pragma unroll
    for (int off = 1; off < 64; off <<= 1) {
        s += __shfl_xor(s, off);
        ss += __shfl_xor(ss, off);
    }
    float mean = s * (1.f / 256.f);
    float var = ss * (1.f / 256.f) - mean * mean;
    float inv = rsqrtf(var + 1e-5f);
    int d = lane * 4;
    float4 g4 = *(const float4*)(g + d);
    float4 b4 = *(const float4*)(bta + d);
    float4 o;
    o.x = (z0 - mean) * inv * g4.x + b4.x;
    o.y = (z1 - mean) * inv * g4.y + b4.y;
    o.z = (z2 - mean) * inv * g4.z + b4.z;
    o.w = (z3 - mean) * inv * g4.w + b4.w;
    *(float4*)(out + (size_t)row * D_ + d) = o;
}

// ---------------------------------------------------------------------------
// Kernel 5: out[b] = dot(h[b, SEQ-1, :], outW) * (1-0.5) + outb[0]
// ---------------------------------------------------------------------------
__global__ __launch_bounds__(128) void final_kernel(
    const float* __restrict__ h, const float* __restrict__ outW,
    const float* __restrict__ outb, float* __restrict__ out)
{
    int b = threadIdx.x >> 6, lane = threadIdx.x & 63;
    const float* hp = h + ((size_t)(b * SEQ_ + SEQ_ - 1)) * D_;
    float4 h4 = *(const float4*)(hp + lane * 4);
    float4 w4 = *(const float4*)(outW + lane * 4);
    float s = h4.x * w4.x + h4.y * w4.y + h4.z * w4.z + h4.w * w4.w;
#pragma unroll
    for (int off = 1; off < 64; off <<= 1) s += __shfl_xor(s, off);
    if (lane == 0) out[b] = s * 0.5f + outb[0];
}

// ---------------------------------------------------------------------------
extern "C" void kernel_launch(void* const* d_in, const int* in_sizes, int n_in,
                              void* d_out, int out_size, void* d_ws, size_t ws_size,
                              hipStream_t stream)
{
    (void)in_sizes; (void)n_in; (void)out_size; (void)ws_size;
    const float* x      = (const float*)d_in[0];
    const float* conv_w = (const float*)d_in[1];
    const float* conv_b = (const float*)d_in[2];
    const float* bn_g   = (const float*)d_in[3];
    const float* bn_b   = (const float*)d_in[4];
    const float* pe     = (const float*)d_in[5];
    const float* qW     = (const float*)d_in[6];
    const float* qb     = (const float*)d_in[7];
    const float* kW     = (const float*)d_in[8];
    const float* kb     = (const float*)d_in[9];
    const float* vW     = (const float*)d_in[10];
    const float* vb     = (const float*)d_in[11];
    const float* oW     = (const float*)d_in[12];
    const float* ob     = (const float*)d_in[13];
    const float* scale  = (const float*)d_in[14];
    const float* td     = (const float*)d_in[15];
    const float* ln1g   = (const float*)d_in[16];
    const float* ln1b   = (const float*)d_in[17];
    const float* f1W    = (const float*)d_in[18];
    const float* f1b    = (const float*)d_in[19];
    const float* f2W    = (const float*)d_in[20];
    const float* f2b    = (const float*)d_in[21];
    const float* ln2g   = (const float*)d_in[22];
    const float* ln2b   = (const float*)d_in[23];
    const float* outW   = (const float*)d_in[24];
    const float* outb   = (const float*)d_in[25];
    float* out = (float*)d_out;

    float* ws = (float*)d_ws;
    const size_t MT = (size_t)B_ * SEQ_ * D_;      // 1M floats
    float* h   = ws;
    float* qs  = ws + MT;
    float* ks  = ws + 2 * MT;
    float* vs  = ws + 3 * MT;
    float* ctx = ws + 4 * MT;
    float* tmp = ws + 5 * MT;
    float* ff1 = ws + 6 * MT;                      // 4M floats
    float* vtail = ws + 10 * MT;                   // B*H*32 floats

    const int Mrows = B_ * SEQ_;                   // 4096

    conv_pe_kernel<<<(B_ * SEQ_ * D_) / 256, 256, 0, stream>>>(
        x, conv_w, conv_b, bn_g, bn_b, pe, h);

    for (int l = 0; l < L_; ++l) {
        dim3 gD(D_ / 64, Mrows / 64);              // 4 x 64
        gemm_bf16<<<gD, 256, 0, stream>>>(h, qW + l * D_ * D_, qb + l * D_, qs,
                                          Mrows, D_, D_, 0);
        gemm_bf16<<<gD, 256, 0, stream>>>(h, kW + l * D_ * D_, kb + l * D_, ks,
                                          Mrows, D_, D_, 0);
        gemm_bf16<<<gD, 256, 0, stream>>>(h, vW + l * D_ * D_, vb + l * D_, vs,
                                          Mrows, D_, D_, 0);

        hipMemsetAsync(vtail, 0, (size_t)B_ * H_ * DK_ * sizeof(float), stream);
        vtail_kernel<<<dim3(H_, B_, 32), 256, 0, stream>>>(vs, td + l * H_, vtail);
        attn_kernel<<<dim3(SEQ_ / 128, H_, B_), 128, 0, stream>>>(
            qs, ks, vs, vtail, ctx, scale + l, td + l * H_);

        gemm_bf16<<<gD, 256, 0, stream>>>(ctx, oW + l * D_ * D_, ob + l * D_, tmp,
                                          Mrows, D_, D_, 0);
        add_ln_kernel<<<Mrows / 4, 256, 0, stream>>>(h, tmp, ln1g + l * D_, ln1b + l * D_, h);

        dim3 gF1(DFF_ / 64, Mrows / 64);           // 16 x 64
        gemm_bf16<<<gF1, 256, 0, stream>>>(h, f1W + l * DFF_ * D_, f1b + l * DFF_, ff1,
                                           Mrows, DFF_, D_, 1);
        gemm_bf16<<<gD, 256, 0, stream>>>(ff1, f2W + l * D_ * DFF_, f2b + l * D_, tmp,
                                          Mrows, D_, DFF_, 0);
        add_ln_kernel<<<Mrows / 4, 256, 0, stream>>>(h, tmp, ln2g + l * D_, ln2b + l * D_, h);
    }

    final_kernel<<<1, 128, 0, stream>>>(h, outW, outb, out);
}

// Round 4
// 275.052 us; speedup vs baseline: 3.6127x; 1.3022x over previous
//
#include <hip/hip_runtime.h>
#include <math.h>

#define B_    2
#define SEQ_  2048
#define D_    256
#define H_    8
#define DK_   32
#define L_    2
#define DFF_  1024

// decay cutoff: exp(-44) ~ 8e-20, below fp32 noise for any plausible score scale
#define TD_CUT 44.0f

typedef short  bf16x8 __attribute__((ext_vector_type(8)));
typedef float  f32x4  __attribute__((ext_vector_type(4)));

__device__ __forceinline__ int compute_kcut(float tdv) {
    int kcut = SEQ_;
    if (tdv > 1e-9f) {
        float kc = TD_CUT / tdv;
        kcut = (kc >= (float)SEQ_) ? SEQ_ : ((int)kc + 1);
    }
    int kcr = (kcut + 31) & ~31;          // round up to tile size
    if (kcr > SEQ_) kcr = SEQ_;
    return kcr;
}

__device__ __forceinline__ unsigned short f2bf(float f) {
    unsigned int u = __float_as_uint(f);
    unsigned int r = u + 0x7FFFu + ((u >> 16) & 1u);   // round-to-nearest-even
    return (unsigned short)(r >> 16);
}

// async 16B global -> LDS DMA (dest = wave-uniform base + lane*16)
__device__ __forceinline__ void gload_lds16(const unsigned short* g, unsigned short* l) {
    __builtin_amdgcn_global_load_lds(
        (const __attribute__((address_space(1))) unsigned int*)(const unsigned int*)g,
        (__attribute__((address_space(3))) unsigned int*)(unsigned int*)l,
        16, 0, 0);
}

// ---------------------------------------------------------------------------
// Kernel 0: fp32 -> bf16 weight pre-convert (all 6 weight tensors, both layers)
// sizes: qW/kW/vW/oW = 131072 each, f1W/f2W = 524288 each; 8 elems/thread.
// ---------------------------------------------------------------------------
__global__ __launch_bounds__(256) void cvt_kernel(
    const float* __restrict__ p0, const float* __restrict__ p1,
    const float* __restrict__ p2, const float* __restrict__ p3,
    const float* __restrict__ p4, const float* __restrict__ p5,
    unsigned short* __restrict__ q0, unsigned short* __restrict__ q1,
    unsigned short* __restrict__ q2, unsigned short* __restrict__ q3,
    unsigned short* __restrict__ q4, unsigned short* __restrict__ q5)
{
    int t = blockIdx.x * 256 + threadIdx.x;        // chunk of 8 elems
    const float* src; unsigned short* dst; int base;
    if (t < 65536) {
        int a = t >> 14;                           // 0..3
        src = a == 0 ? p0 : a == 1 ? p1 : a == 2 ? p2 : p3;
        dst = a == 0 ? q0 : a == 1 ? q1 : a == 2 ? q2 : q3;
        base = (t & 16383) * 8;
    } else {
        int u = t - 65536;
        int a = u >> 16;                           // 0..1
        src = a ? p5 : p4;
        dst = a ? q5 : q4;
        base = (u & 65535) * 8;
    }
    float4 v0 = *(const float4*)(src + base);
    float4 v1 = *(const float4*)(src + base + 4);
    bf16x8 o;
    o[0] = (short)f2bf(v0.x); o[1] = (short)f2bf(v0.y);
    o[2] = (short)f2bf(v0.z); o[3] = (short)f2bf(v0.w);
    o[4] = (short)f2bf(v1.x); o[5] = (short)f2bf(v1.y);
    o[6] = (short)f2bf(v1.z); o[7] = (short)f2bf(v1.w);
    *(bf16x8*)(dst + base) = o;
}

// ---------------------------------------------------------------------------
// Kernel 1: conv1d(K=3, SAME) + bias + affine + relu + pe; fp32 + bf16 out.
// ---------------------------------------------------------------------------
__global__ __launch_bounds__(256) void conv_pe_kernel(
    const float* __restrict__ x, const float* __restrict__ w,
    const float* __restrict__ cb, const float* __restrict__ bg,
    const float* __restrict__ bb, const float* __restrict__ pe,
    float* __restrict__ h, unsigned short* __restrict__ hbf)
{
    int idx = blockIdx.x * 256 + threadIdx.x;      // b*SEQ*D + s*D + d
    int d = idx & 255;
    int s = (idx >> 8) & 2047;
    int b = idx >> 19;

    const float* xp = x + b * SEQ_;
    float xm1 = (s > 0)        ? xp[s - 1] : 0.f;
    float x0  = xp[s];
    float xp1 = (s < SEQ_ - 1) ? xp[s + 1] : 0.f;

    float acc = xm1 * w[d * 3 + 0] + x0 * w[d * 3 + 1] + xp1 * w[d * 3 + 2];
    acc += cb[d];
    acc = acc * rsqrtf(1.f + 1e-5f) * bg[d] + bb[d];
    acc = fmaxf(acc, 0.f);
    float v = acc + pe[s * D_ + d];
    h[idx] = v;
    hbf[idx] = f2bf(v);
}

// ---------------------------------------------------------------------------
// Kernel 2: bf16-MFMA GEMM  C[m,n] = sum_k A[m,k]*B[n,k] + bias[n].
// A: MxK bf16 row-major, W: NxK bf16 row-major (A @ W^T).
// blockIdx.z selects (W,bias,C) -> fused q/k/v in one dispatch.
// 64x64 tile, BK=32, 4 waves 2x2 of 32x32. Staging via global_load_lds 16B,
// unpadded LDS (64x32 shorts), XOR col-block swizzle (cb ^= row&3).
// fp32out: write fp32 C; Cbf nonnull: also write bf16 copy.
// ---------------------------------------------------------------------------
__global__ __launch_bounds__(256) void gemm_bf16(
    const unsigned short* __restrict__ A,
    const unsigned short* __restrict__ W0, const unsigned short* __restrict__ W1,
    const unsigned short* __restrict__ W2,
    const float* __restrict__ b0, const float* __restrict__ b1,
    const float* __restrict__ b2,
    float* __restrict__ C0, float* __restrict__ C1, float* __restrict__ C2,
    unsigned short* __restrict__ Cbf,
    int M, int N, int K, int relu, int fp32out)
{
    int z = blockIdx.z;
    const unsigned short* W = (z == 0) ? W0 : (z == 1) ? W1 : W2;
    const float* bias = (z == 0) ? b0 : (z == 1) ? b1 : b2;
    float* C = (z == 0) ? C0 : (z == 1) ? C1 : C2;

    __shared__ unsigned short As[64 * 32];
    __shared__ unsigned short Bs[64 * 32];

    int tid  = threadIdx.x;
    int wave = tid >> 6, lane = tid & 63;
    int wm = (wave & 1) * 32, wn = (wave >> 1) * 32;
    int bm = blockIdx.y * 64, bn = blockIdx.x * 64;

    // staging: thread t owns LDS 16B slot t -> row sr=t>>2, stored col-block t&3.
    // stored col-block (t&3) holds global col-block (t&3)^(sr&3).
    int sr  = tid >> 2;
    int scb = (tid & 3) ^ (sr & 3);
    const unsigned short* aG = A + (size_t)(bm + sr) * K + scb * 8;
    const unsigned short* wG = W + (size_t)(bn + sr) * K + scb * 8;
    unsigned short* aL = &As[tid * 8];
    unsigned short* bL = &Bs[tid * 8];

    // fragment offsets: row fr (+16), global k-block kb -> stored block kb^(fr&3)
    int fr = lane & 15;
    int kb = lane >> 4;
    int cb = (kb ^ (fr & 3)) * 8;
    int oA0 = (wm + fr) * 32 + cb;
    int oA1 = (wm + 16 + fr) * 32 + cb;
    int oB0 = (wn + fr) * 32 + cb;
    int oB1 = (wn + 16 + fr) * 32 + cb;

    f32x4 acc[2][2];
#pragma unroll
    for (int i = 0; i < 2; ++i)
#pragma unroll
        for (int j = 0; j < 2; ++j) acc[i][j] = (f32x4){0.f, 0.f, 0.f, 0.f};

    for (int k0 = 0; k0 < K; k0 += 32) {
        __syncthreads();                 // prev tile's frag reads complete
        gload_lds16(aG + k0, aL);
        gload_lds16(wG + k0, bL);
        __syncthreads();                 // compiler drains vmcnt before barrier

        bf16x8 a0f = *(const bf16x8*)&As[oA0];
        bf16x8 a1f = *(const bf16x8*)&As[oA1];
        bf16x8 b0f = *(const bf16x8*)&Bs[oB0];
        bf16x8 b1f = *(const bf16x8*)&Bs[oB1];

        acc[0][0] = __builtin_amdgcn_mfma_f32_16x16x32_bf16(a0f, b0f, acc[0][0], 0, 0, 0);
        acc[0][1] = __builtin_amdgcn_mfma_f32_16x16x32_bf16(a0f, b1f, acc[0][1], 0, 0, 0);
        acc[1][0] = __builtin_amdgcn_mfma_f32_16x16x32_bf16(a1f, b0f, acc[1][0], 0, 0, 0);
        acc[1][1] = __builtin_amdgcn_mfma_f32_16x16x32_bf16(a1f, b1f, acc[1][1], 0, 0, 0);
    }

    int crow = (lane >> 4) * 4;
    int ccol = lane & 15;
#pragma unroll
    for (int j = 0; j < 2; ++j) {
        float bj = bias[bn + wn + j * 16 + ccol];
#pragma unroll
        for (int i = 0; i < 2; ++i) {
#pragma unroll
            for (int r = 0; r < 4; ++r) {
                float v = acc[i][j][r] + bj;
                if (relu) v = fmaxf(v, 0.f);
                size_t off = (size_t)(bm + wm + i * 16 + crow + r) * N + bn + wn + j * 16 + ccol;
                if (fp32out) C[off] = v;
                if (Cbf) Cbf[off] = f2bf(v);
            }
        }
    }
}

// ---------------------------------------------------------------------------
// Kernel 3a: V-suffix partial sums, atomically accumulated into zeroed vtail.
// ---------------------------------------------------------------------------
__global__ __launch_bounds__(256) void vtail_kernel(
    const float* __restrict__ v, const float* __restrict__ td_l,
    float* __restrict__ vtail)
{
    int hh = blockIdx.x, b = blockIdx.y, z = blockIdx.z;
    int kcr = compute_kcut(td_l[hh]);
    int rbeg = z * 64, rend = rbeg + 64;
    if (rend <= kcr) return;
    int lo = rbeg > kcr ? rbeg : kcr;

    int d = threadIdx.x & 31, c = threadIdx.x >> 5;    // 8 row-chunks
    float s = 0.f;
    for (int k = lo + c; k < rend; k += 8)
        s += v[((size_t)(b * SEQ_ + k)) * D_ + hh * DK_ + d];

    __shared__ float sm[8][32];
    sm[c][d] = s;
    __syncthreads();
    if (threadIdx.x < 32) {
        float t = 0.f;
#pragma unroll
        for (int i = 0; i < 8; ++i) t += sm[i][threadIdx.x];
        atomicAdd(&vtail[((size_t)(b * H_ + hh)) * DK_ + threadIdx.x], t);
    }
}

// ---------------------------------------------------------------------------
// Kernel 3b: decay-truncated flash attention + analytic tail. ctx fp32+bf16.
// ---------------------------------------------------------------------------
__global__ __launch_bounds__(128) void attn_kernel(
    const float* __restrict__ q, const float* __restrict__ k,
    const float* __restrict__ v, const float* __restrict__ vtail,
    float* __restrict__ ctx, unsigned short* __restrict__ ctxbf,
    const float* __restrict__ scale_p, const float* __restrict__ td_l)
{
    int b = blockIdx.z, hh = blockIdx.y;
    int tid = threadIdx.x;
    int qrow = blockIdx.x * 128 + tid;

    float sc  = 0.17677669529663687f * scale_p[0];   // 1/sqrt(32) * scale[l]
    float tdv = td_l[hh];
    int kcr = compute_kcut(tdv);
    int ntiles = kcr >> 5;

    __shared__ float kt[32][36];
    __shared__ float vt[32][36];

    const float* qptr = q + ((size_t)(b * SEQ_ + qrow)) * D_ + hh * DK_;
    float qreg[32];
#pragma unroll
    for (int j = 0; j < 8; ++j) {
        float4 t4 = ((const float4*)qptr)[j];
        qreg[j * 4 + 0] = t4.x; qreg[j * 4 + 1] = t4.y;
        qreg[j * 4 + 2] = t4.z; qreg[j * 4 + 3] = t4.w;
    }
    float O[32];
#pragma unroll
    for (int d = 0; d < 32; ++d) O[d] = 0.f;
    float mrun = -1e30f, lrun = 0.f;

    for (int t = 0; t < ntiles; ++t) {
        int k0 = t * 32;
        __syncthreads();
#pragma unroll
        for (int u = 0; u < 2; ++u) {
            int s4 = tid + u * 128;
            int r = s4 >> 3, c4 = s4 & 7;
            size_t goff = ((size_t)(b * SEQ_ + k0 + r)) * D_ + hh * DK_ + c4 * 4;
            *(float4*)&kt[r][c4 * 4] = *(const float4*)(k + goff);
            *(float4*)&vt[r][c4 * 4] = *(const float4*)(v + goff);
        }
        __syncthreads();

        float sb[32];
        float tmax = -1e30f;
#pragma unroll
        for (int kk = 0; kk < 32; ++kk) {
            float acc = 0.f;
#pragma unroll
            for (int d4 = 0; d4 < 8; ++d4) {
                float4 kv = *(const float4*)&kt[kk][d4 * 4];
                acc += qreg[d4 * 4 + 0] * kv.x + qreg[d4 * 4 + 1] * kv.y
                     + qreg[d4 * 4 + 2] * kv.z + qreg[d4 * 4 + 3] * kv.w;
            }
            float dec = __expf(-tdv * (float)(k0 + kk));
            float sv = acc * sc * dec;
            sb[kk] = sv;
            tmax = fmaxf(tmax, sv);
        }
        float mnew = fmaxf(mrun, tmax);
        float alpha = __expf(mrun - mnew);
        lrun *= alpha;
#pragma unroll
        for (int d = 0; d < 32; ++d) O[d] *= alpha;
#pragma unroll
        for (int kk = 0; kk < 32; ++kk) {
            float sv = sb[kk];
            float e = __expf(sv - mnew);
            float sg = 1.f / (1.f + __expf(-sv));
            float p = e * sg;
            lrun += e;
#pragma unroll
            for (int d4 = 0; d4 < 8; ++d4) {
                float4 vv = *(const float4*)&vt[kk][d4 * 4];
                O[d4 * 4 + 0] += p * vv.x; O[d4 * 4 + 1] += p * vv.y;
                O[d4 * 4 + 2] += p * vv.z; O[d4 * 4 + 3] += p * vv.w;
            }
        }
        mrun = mnew;
    }

    // analytic tail: all keys >= kcr have score exactly 0 (decay underflow)
    if (kcr < SEQ_) {
        float mnew = fmaxf(mrun, 0.f);
        float alpha = __expf(mrun - mnew);
        lrun *= alpha;
        float ew = __expf(-mnew);
        lrun += (float)(SEQ_ - kcr) * ew;
        const float* vtp = vtail + ((size_t)(b * H_ + hh)) * DK_;
        float pw = 0.5f * ew;                // sigmoid(0) = 0.5
#pragma unroll
        for (int d = 0; d < 32; ++d) O[d] = O[d] * alpha + pw * vtp[d];
    }

    float invL = 1.f / lrun;
    size_t obase = ((size_t)(b * SEQ_ + qrow)) * D_ + hh * DK_;
    float* outp = ctx + obase;
    unsigned short* obf = ctxbf + obase;
#pragma unroll
    for (int d4 = 0; d4 < 8; ++d4) {
        float4 o;
        o.x = O[d4 * 4 + 0] * invL; o.y = O[d4 * 4 + 1] * invL;
        o.z = O[d4 * 4 + 2] * invL; o.w = O[d4 * 4 + 3] * invL;
        ((float4*)outp)[d4] = o;
        unsigned int u01 = (unsigned)f2bf(o.x) | ((unsigned)f2bf(o.y) << 16);
        unsigned int u23 = (unsigned)f2bf(o.z) | ((unsigned)f2bf(o.w) << 16);
        ((uint2*)obf)[d4] = make_uint2(u01, u23);
    }
}

// ---------------------------------------------------------------------------
// Kernel 4: out = LayerNorm(resid + add) * g + b; fp32 + bf16 out.
// ---------------------------------------------------------------------------
__global__ __launch_bounds__(256) void add_ln_kernel(
    const float* __restrict__ resid, const float* __restrict__ add,
    const float* __restrict__ g, const float* __restrict__ bta,
    float* __restrict__ out, unsigned short* __restrict__ outbf)
{
    int row = blockIdx.x * 4 + (threadIdx.x >> 6);
    int lane = threadIdx.x & 63;
    const float* rp = resid + (size_t)row * D_;
    const float* ap = add + (size_t)row * D_;
    float4 r4 = *(const float4*)(rp + lane * 4);
    float4 a4 = *(const float4*)(ap + lane * 4);
    float z0 = r4.x + a4.x, z1 = r4.y + a4.y, z2 = r4.z + a4.z, z3 = r4.w + a4.w;
    float s = z0 + z1 + z2 + z3;
    float ss = z0 * z0 + z1 * z1 + z2 * z2 + z3 * z3;
#pragma unroll
    for (int off = 1; off < 64; off <<= 1) {
        s += __shfl_xor(s, off);
        ss += __shfl_xor(ss, off);
    }
    float mean = s * (1.f / 256.f);
    float var = ss * (1.f / 256.f) - mean * mean;
    float inv = rsqrtf(var + 1e-5f);
    int d = lane * 4;
    float4 g4 = *(const float4*)(g + d);
    float4 b4 = *(const float4*)(bta + d);
    float4 o;
    o.x = (z0 - mean) * inv * g4.x + b4.x;
    o.y = (z1 - mean) * inv * g4.y + b4.y;
    o.z = (z2 - mean) * inv * g4.z + b4.z;
    o.w = (z3 - mean) * inv * g4.w + b4.w;
    *(float4*)(out + (size_t)row * D_ + d) = o;
    unsigned int u01 = (unsigned)f2bf(o.x) | ((unsigned)f2bf(o.y) << 16);
    unsigned int u23 = (unsigned)f2bf(o.z) | ((unsigned)f2bf(o.w) << 16);
    *(uint2*)&outbf[(size_t)row * D_ + d] = make_uint2(u01, u23);
}

// ---------------------------------------------------------------------------
// Kernel 5: out[b] = dot(h[b, SEQ-1, :], outW) * (1-0.5) + outb[0]
// ---------------------------------------------------------------------------
__global__ __launch_bounds__(128) void final_kernel(
    const float* __restrict__ h, const float* __restrict__ outW,
    const float* __restrict__ outb, float* __restrict__ out)
{
    int b = threadIdx.x >> 6, lane = threadIdx.x & 63;
    const float* hp = h + ((size_t)(b * SEQ_ + SEQ_ - 1)) * D_;
    float4 h4 = *(const float4*)(hp + lane * 4);
    float4 w4 = *(const float4*)(outW + lane * 4);
    float s = h4.x * w4.x + h4.y * w4.y + h4.z * w4.z + h4.w * w4.w;
#pragma unroll
    for (int off = 1; off < 64; off <<= 1) s += __shfl_xor(s, off);
    if (lane == 0) out[b] = s * 0.5f + outb[0];
}

// ---------------------------------------------------------------------------
extern "C" void kernel_launch(void* const* d_in, const int* in_sizes, int n_in,
                              void* d_out, int out_size, void* d_ws, size_t ws_size,
                              hipStream_t stream)
{
    (void)in_sizes; (void)n_in; (void)out_size; (void)ws_size;
    const float* x      = (const float*)d_in[0];
    const float* conv_w = (const float*)d_in[1];
    const float* conv_b = (const float*)d_in[2];
    const float* bn_g   = (const float*)d_in[3];
    const float* bn_b   = (const float*)d_in[4];
    const float* pe     = (const float*)d_in[5];
    const float* qW     = (const float*)d_in[6];
    const float* qb     = (const float*)d_in[7];
    const float* kW     = (const float*)d_in[8];
    const float* kb     = (const float*)d_in[9];
    const float* vW     = (const float*)d_in[10];
    const float* vb     = (const float*)d_in[11];
    const float* oW     = (const float*)d_in[12];
    const float* ob     = (const float*)d_in[13];
    const float* scale  = (const float*)d_in[14];
    const float* td     = (const float*)d_in[15];
    const float* ln1g   = (const float*)d_in[16];
    const float* ln1b   = (const float*)d_in[17];
    const float* f1W    = (const float*)d_in[18];
    const float* f1b    = (const float*)d_in[19];
    const float* f2W    = (const float*)d_in[20];
    const float* f2b    = (const float*)d_in[21];
    const float* ln2g   = (const float*)d_in[22];
    const float* ln2b   = (const float*)d_in[23];
    const float* outW   = (const float*)d_in[24];
    const float* outb   = (const float*)d_in[25];
    float* out = (float*)d_out;

    float* ws = (float*)d_ws;
    const size_t MT = (size_t)B_ * SEQ_ * D_;      // 1,048,576
    float* h     = ws;
    float* qs    = ws + MT;
    float* ks    = ws + 2 * MT;
    float* vs    = ws + 3 * MT;
    float* ctx   = ws + 4 * MT;
    float* tmp   = ws + 5 * MT;
    float* vtail = ws + 6 * MT;                    // 1024 floats
    unsigned short* bfb   = (unsigned short*)(ws + 7 * MT);
    unsigned short* h_bf   = bfb;                  // MT
    unsigned short* ctx_bf = bfb + MT;             // MT
    unsigned short* ff1_bf = bfb + 2 * MT;         // 4*MT (M x DFF)
    unsigned short* wq_bf  = bfb + 6 * MT;         // L*D*D = MT/8 each
    unsigned short* wk_bf  = wq_bf + MT / 8;
    unsigned short* wv_bf  = wk_bf + MT / 8;
    unsigned short* wo_bf  = wv_bf + MT / 8;
    unsigned short* wf1_bf = wo_bf + MT / 8;       // L*DFF*D = MT/2
    unsigned short* wf2_bf = wf1_bf + MT / 2;

    const int Mrows = B_ * SEQ_;                   // 4096

    cvt_kernel<<<768, 256, 0, stream>>>(qW, kW, vW, oW, f1W, f2W,
                                        wq_bf, wk_bf, wv_bf, wo_bf, wf1_bf, wf2_bf);

    conv_pe_kernel<<<(B_ * SEQ_ * D_) / 256, 256, 0, stream>>>(
        x, conv_w, conv_b, bn_g, bn_b, pe, h, h_bf);

    for (int l = 0; l < L_; ++l) {
        const unsigned short* wq_l  = wq_bf  + (size_t)l * D_ * D_;
        const unsigned short* wk_l  = wk_bf  + (size_t)l * D_ * D_;
        const unsigned short* wv_l  = wv_bf  + (size_t)l * D_ * D_;
        const unsigned short* wo_l  = wo_bf  + (size_t)l * D_ * D_;
        const unsigned short* wf1_l = wf1_bf + (size_t)l * DFF_ * D_;
        const unsigned short* wf2_l = wf2_bf + (size_t)l * DFF_ * D_;

        // fused q,k,v: blockIdx.z selects weight/bias/output
        gemm_bf16<<<dim3(D_ / 64, Mrows / 64, 3), 256, 0, stream>>>(
            h_bf, wq_l, wk_l, wv_l, qb + l * D_, kb + l * D_, vb + l * D_,
            qs, ks, vs, nullptr, Mrows, D_, D_, 0, 1);

        hipMemsetAsync(vtail, 0, (size_t)B_ * H_ * DK_ * sizeof(float), stream);
        vtail_kernel<<<dim3(H_, B_, 32), 256, 0, stream>>>(vs, td + l * H_, vtail);
        attn_kernel<<<dim3(SEQ_ / 128, H_, B_), 128, 0, stream>>>(
            qs, ks, vs, vtail, ctx, ctx_bf, scale + l, td + l * H_);

        gemm_bf16<<<dim3(D_ / 64, Mrows / 64, 1), 256, 0, stream>>>(
            ctx_bf, wo_l, wo_l, wo_l, ob + l * D_, ob + l * D_, ob + l * D_,
            tmp, tmp, tmp, nullptr, Mrows, D_, D_, 0, 1);
        add_ln_kernel<<<Mrows / 4, 256, 0, stream>>>(h, tmp, ln1g + l * D_, ln1b + l * D_, h, h_bf);

        // FFN1: bf16-only output (consumed only by FFN2)
        gemm_bf16<<<dim3(DFF_ / 64, Mrows / 64, 1), 256, 0, stream>>>(
            h_bf, wf1_l, wf1_l, wf1_l, f1b + l * DFF_, f1b + l * DFF_, f1b + l * DFF_,
            tmp, tmp, tmp, ff1_bf, Mrows, DFF_, D_, 1, 0);
        gemm_bf16<<<dim3(D_ / 64, Mrows / 64, 1), 256, 0, stream>>>(
            ff1_bf, wf2_l, wf2_l, wf2_l, f2b + l * D_, f2b + l * D_, f2b + l * D_,
            tmp, tmp, tmp, nullptr, Mrows, D_, DFF_, 0, 1);
        add_ln_kernel<<<Mrows / 4, 256, 0, stream>>>(h, tmp, ln2g + l * D_, ln2b + l * D_, h, h_bf);
    }

    final_kernel<<<1, 128, 0, stream>>>(h, outW, outb, out);
}